// Round 1
// baseline (48979.727 us; speedup 1.0000x reference)
//
#include <hip/hip_runtime.h>

#define HID 32
#define NFEAT 64

// ---------------------------------------------------------------------------
// Graph preprocessing (loop-invariant, rebuilt every launch)
// ---------------------------------------------------------------------------

__global__ void hist_kernel(const int* __restrict__ dstP, const int* __restrict__ dstN,
                            int* __restrict__ cntP, int* __restrict__ cntN, int E) {
    int stride = gridDim.x * blockDim.x;
    for (int idx = blockIdx.x * blockDim.x + threadIdx.x; idx < 2 * E; idx += stride) {
        if (idx < E) atomicAdd(&cntP[dstP[idx]], 1);
        else         atomicAdd(&cntN[dstN[idx - E]], 1);
    }
}

__global__ void deg_kernel(const int* __restrict__ cntP, const int* __restrict__ cntN,
                           float* __restrict__ dinvP, float* __restrict__ invdegP,
                           float* __restrict__ dinvN, float* __restrict__ invdegN, int n) {
    int i = blockIdx.x * blockDim.x + threadIdx.x;
    if (i >= n) return;
    float dp = (float)cntP[i] + 1.0f;
    dinvP[i] = rsqrtf(dp);
    invdegP[i] = 1.0f / dp;
    float dn = (float)cntN[i] + 1.0f;
    dinvN[i] = rsqrtf(dn);
    invdegN[i] = 1.0f / dn;
}

// Exclusive scan of cnt -> row_ptr (one block per graph, sequential chunks).
__global__ void scan_kernel(const int* __restrict__ cntP, const int* __restrict__ cntN,
                            int* __restrict__ rpP, int* __restrict__ rpN, int n) {
    const int* cnt = blockIdx.x ? cntN : cntP;
    int* rp = blockIdx.x ? rpN : rpP;
    __shared__ int buf[1024];
    __shared__ int carry;
    int tid = threadIdx.x;
    if (tid == 0) carry = 0;
    __syncthreads();
    for (int base = 0; base < n; base += 1024) {
        int i = base + tid;
        int v = (i < n) ? cnt[i] : 0;
        buf[tid] = v;
        __syncthreads();
        for (int off = 1; off < 1024; off <<= 1) {
            int t = (tid >= off) ? buf[tid - off] : 0;
            __syncthreads();
            buf[tid] += t;
            __syncthreads();
        }
        int c = carry;
        if (i < n) rp[i] = c + buf[tid] - v;   // exclusive
        __syncthreads();
        if (tid == 1023) carry = c + buf[1023];
        __syncthreads();
    }
    if (tid == 0) rp[n] = carry;
}

__global__ void fill_kernel(const int* __restrict__ srcP, const int* __restrict__ dstP,
                            const int* __restrict__ srcN, const int* __restrict__ dstN,
                            const float* __restrict__ dinvP, const float* __restrict__ dinvN,
                            int* __restrict__ curP, int* __restrict__ curN,
                            int* __restrict__ colP, float* __restrict__ cofP,
                            int* __restrict__ colN, float* __restrict__ cofN, int E) {
    int stride = gridDim.x * blockDim.x;
    for (int idx = blockIdx.x * blockDim.x + threadIdx.x; idx < 2 * E; idx += stride) {
        if (idx < E) {
            int s = srcP[idx], d = dstP[idx];
            int p = atomicAdd(&curP[d], 1);
            colP[p] = s;
            cofP[p] = dinvP[s] * dinvP[d];
        } else {
            int e = idx - E;
            int s = srcN[e], d = dstN[e];
            int p = atomicAdd(&curN[d], 1);
            colN[p] = s;
            cofN[p] = dinvN[s] * dinvN[d];
        }
    }
}

// ---------------------------------------------------------------------------
// Encoder: h0 = LN(x @ w_enc + b_enc; g_feat,b_feat); also hn = LN(h0; g_ode,b_ode)
// ---------------------------------------------------------------------------

__global__ __launch_bounds__(256) void encoder_kernel(
        const float* __restrict__ x, const float* __restrict__ w_enc,
        const float* __restrict__ b_enc, const float* __restrict__ g_feat,
        const float* __restrict__ b_feat, const float* __restrict__ g_ode,
        const float* __restrict__ b_ode,
        float* __restrict__ h, float* __restrict__ hn, int n) {
    __shared__ float sW[NFEAT][HID];
    __shared__ float sBe[HID], sGf[HID], sBf[HID], sGo[HID], sBo[HID];
    for (int k = threadIdx.x; k < NFEAT * HID; k += blockDim.x)
        sW[k / HID][k % HID] = w_enc[k];
    if (threadIdx.x < HID) {
        sBe[threadIdx.x] = b_enc[threadIdx.x];
        sGf[threadIdx.x] = g_feat[threadIdx.x];
        sBf[threadIdx.x] = b_feat[threadIdx.x];
        sGo[threadIdx.x] = g_ode[threadIdx.x];
        sBo[threadIdx.x] = b_ode[threadIdx.x];
    }
    __syncthreads();
    int i = blockIdx.x * blockDim.x + threadIdx.x;
    if (i >= n) return;

    float acc[HID];
    #pragma unroll
    for (int f = 0; f < HID; ++f) acc[f] = sBe[f];
    const float4* xr = reinterpret_cast<const float4*>(x + (size_t)i * NFEAT);
    #pragma unroll
    for (int q = 0; q < NFEAT / 4; ++q) {
        float4 xv = xr[q];
        #pragma unroll
        for (int f = 0; f < HID; ++f)
            acc[f] += xv.x * sW[4*q+0][f] + xv.y * sW[4*q+1][f]
                    + xv.z * sW[4*q+2][f] + xv.w * sW[4*q+3][f];
    }
    // LN (feat)
    float m = 0.f;
    #pragma unroll
    for (int f = 0; f < HID; ++f) m += acc[f];
    m *= (1.0f / HID);
    float var = 0.f;
    #pragma unroll
    for (int f = 0; f < HID; ++f) { float d = acc[f] - m; var += d * d; }
    var *= (1.0f / HID);
    float rs = rsqrtf(var + 1e-5f);
    #pragma unroll
    for (int f = 0; f < HID; ++f) acc[f] = (acc[f] - m) * rs * sGf[f] + sBf[f];

    float4* hw = reinterpret_cast<float4*>(h + (size_t)i * HID);
    #pragma unroll
    for (int q = 0; q < HID / 4; ++q)
        hw[q] = make_float4(acc[4*q], acc[4*q+1], acc[4*q+2], acc[4*q+3]);

    // LN (ode) -> hn
    m = 0.f;
    #pragma unroll
    for (int f = 0; f < HID; ++f) m += acc[f];
    m *= (1.0f / HID);
    var = 0.f;
    #pragma unroll
    for (int f = 0; f < HID; ++f) { float d = acc[f] - m; var += d * d; }
    var *= (1.0f / HID);
    rs = rsqrtf(var + 1e-5f);
    float4* hnw = reinterpret_cast<float4*>(hn + (size_t)i * HID);
    #pragma unroll
    for (int q = 0; q < HID / 4; ++q)
        hnw[q] = make_float4((acc[4*q+0] - m) * rs * sGo[4*q+0] + sBo[4*q+0],
                             (acc[4*q+1] - m) * rs * sGo[4*q+1] + sBo[4*q+1],
                             (acc[4*q+2] - m) * rs * sGo[4*q+2] + sBo[4*q+2],
                             (acc[4*q+3] - m) * rs * sGo[4*q+3] + sBo[4*q+3]);
}

// ---------------------------------------------------------------------------
// SpMM over hn (both graphs in one grid): agg[i] = invdeg[i]*hn[i] + sum coef*hn[col]
// 32 lanes per node, coalesced 128B gathers.
// ---------------------------------------------------------------------------

__global__ __launch_bounds__(256) void spmm_kernel(
        const float* __restrict__ hn,
        const int* __restrict__ rpP, const int* __restrict__ colP,
        const float* __restrict__ cofP, const float* __restrict__ invdegP,
        const int* __restrict__ rpN, const int* __restrict__ colN,
        const float* __restrict__ cofN, const float* __restrict__ invdegN,
        float* __restrict__ aggp, float* __restrict__ aggn, int n, int nbg) {
    int b = blockIdx.x;
    int graph = (b >= nbg);
    if (graph) b -= nbg;
    int i = b * 8 + (threadIdx.x >> 5);
    int f = threadIdx.x & 31;
    if (i >= n) return;
    const int*   rp  = graph ? rpN  : rpP;
    const int*   col = graph ? colN : colP;
    const float* cof = graph ? cofN : cofP;
    const float* ivd = graph ? invdegN : invdegP;
    float*       out = graph ? aggn : aggp;
    int beg = rp[i], end = rp[i + 1];
    float acc = ivd[i] * hn[(size_t)i * HID + f];
    for (int e = beg; e < end; ++e) {
        int j = col[e];
        float c = cof[e];
        acc += c * hn[(size_t)j * HID + f];
    }
    out[(size_t)i * HID + f] = acc;
}

// ---------------------------------------------------------------------------
// Fused pointwise kernel: matmuls + tanh + clip + RK4 stage + LN of next state
// ---------------------------------------------------------------------------

template<int STAGE, bool LAST>
__global__ __launch_bounds__(256) void post_kernel(
        const float* __restrict__ aggp, const float* __restrict__ aggn,
        const float* __restrict__ w_pos, const float* __restrict__ b_pos,
        const float* __restrict__ w_neg, const float* __restrict__ b_neg,
        const float* __restrict__ w_psi,
        const float* __restrict__ g_ode, const float* __restrict__ b_ode,
        const float* __restrict__ t,
        float* __restrict__ h, float* __restrict__ hn, float* __restrict__ kacc,
        float* __restrict__ out, int n) {
    __shared__ float sWp[HID][HID];
    __shared__ float sWn[HID][HID];
    __shared__ float sPsi[2 * HID][HID];
    __shared__ float sBp[HID], sBn[HID], sGo[HID], sBo[HID];
    for (int k = threadIdx.x; k < HID * HID; k += blockDim.x) {
        sWp[k / HID][k % HID] = w_pos[k];
        sWn[k / HID][k % HID] = w_neg[k];
    }
    for (int k = threadIdx.x; k < 2 * HID * HID; k += blockDim.x)
        sPsi[k / HID][k % HID] = w_psi[k];
    if (threadIdx.x < HID) {
        sBp[threadIdx.x] = b_pos[threadIdx.x];
        sBn[threadIdx.x] = b_neg[threadIdx.x];
        sGo[threadIdx.x] = g_ode[threadIdx.x];
        sBo[threadIdx.x] = b_ode[threadIdx.x];
    }
    __syncthreads();
    int i = blockIdx.x * blockDim.x + threadIdx.x;
    if (i >= n) return;
    const float dt = (t[1] - t[0]) * 0.125f;

    float acc[HID];
    #pragma unroll
    for (int f = 0; f < HID; ++f) acc[f] = 0.0f;

    {   // hp = aggp @ w_pos + b_pos ; acc += hp @ psi_top
        float hp[HID];
        #pragma unroll
        for (int f = 0; f < HID; ++f) hp[f] = sBp[f];
        const float4* ar = reinterpret_cast<const float4*>(aggp + (size_t)i * HID);
        #pragma unroll
        for (int q = 0; q < HID / 4; ++q) {
            float4 a = ar[q];
            #pragma unroll
            for (int f = 0; f < HID; ++f)
                hp[f] += a.x * sWp[4*q+0][f] + a.y * sWp[4*q+1][f]
                       + a.z * sWp[4*q+2][f] + a.w * sWp[4*q+3][f];
        }
        #pragma unroll
        for (int k = 0; k < HID; ++k) {
            #pragma unroll
            for (int f = 0; f < HID; ++f) acc[f] += hp[k] * sPsi[k][f];
        }
    }
    {   // hm = aggn @ w_neg + b_neg ; acc += hm @ psi_bottom
        float hm[HID];
        #pragma unroll
        for (int f = 0; f < HID; ++f) hm[f] = sBn[f];
        const float4* ar = reinterpret_cast<const float4*>(aggn + (size_t)i * HID);
        #pragma unroll
        for (int q = 0; q < HID / 4; ++q) {
            float4 a = ar[q];
            #pragma unroll
            for (int f = 0; f < HID; ++f)
                hm[f] += a.x * sWn[4*q+0][f] + a.y * sWn[4*q+1][f]
                       + a.z * sWn[4*q+2][f] + a.w * sWn[4*q+3][f];
        }
        #pragma unroll
        for (int k = 0; k < HID; ++k) {
            #pragma unroll
            for (int f = 0; f < HID; ++f) acc[f] += hm[k] * sPsi[HID + k][f];
        }
    }
    // k = clip(tanh(acc) - 0.1*hn, -50, 50)   (acc := k)
    {
        const float4* hr = reinterpret_cast<const float4*>(hn + (size_t)i * HID);
        #pragma unroll
        for (int q = 0; q < HID / 4; ++q) {
            float4 hv = hr[q];
            float d0 = tanhf(acc[4*q+0]) - 0.1f * hv.x;
            float d1 = tanhf(acc[4*q+1]) - 0.1f * hv.y;
            float d2 = tanhf(acc[4*q+2]) - 0.1f * hv.z;
            float d3 = tanhf(acc[4*q+3]) - 0.1f * hv.w;
            acc[4*q+0] = fminf(fmaxf(d0, -50.0f), 50.0f);
            acc[4*q+1] = fminf(fmaxf(d1, -50.0f), 50.0f);
            acc[4*q+2] = fminf(fmaxf(d2, -50.0f), 50.0f);
            acc[4*q+3] = fminf(fmaxf(d3, -50.0f), 50.0f);
        }
    }
    // RK4 stage; acc := h_next (input to next ode eval)
    float4* kar = reinterpret_cast<float4*>(kacc + (size_t)i * HID);
    const float4* hbr = reinterpret_cast<const float4*>(h + (size_t)i * HID);
    #pragma unroll
    for (int q = 0; q < HID / 4; ++q) {
        float4 hb = hbr[q];
        float4 k4 = make_float4(acc[4*q], acc[4*q+1], acc[4*q+2], acc[4*q+3]);
        if (STAGE == 0) {
            kar[q] = k4;
            acc[4*q+0] = hb.x + 0.5f * dt * k4.x;
            acc[4*q+1] = hb.y + 0.5f * dt * k4.y;
            acc[4*q+2] = hb.z + 0.5f * dt * k4.z;
            acc[4*q+3] = hb.w + 0.5f * dt * k4.w;
        } else if (STAGE == 1 || STAGE == 2) {
            float4 ka = kar[q];
            ka.x += 2.0f * k4.x; ka.y += 2.0f * k4.y;
            ka.z += 2.0f * k4.z; ka.w += 2.0f * k4.w;
            kar[q] = ka;
            const float a = (STAGE == 1) ? 0.5f * dt : dt;
            acc[4*q+0] = hb.x + a * k4.x;
            acc[4*q+1] = hb.y + a * k4.y;
            acc[4*q+2] = hb.z + a * k4.z;
            acc[4*q+3] = hb.w + a * k4.w;
        } else {
            float4 ka = kar[q];
            const float c = dt * (1.0f / 6.0f);
            float4 hnew = make_float4(hb.x + c * (ka.x + k4.x),
                                      hb.y + c * (ka.y + k4.y),
                                      hb.z + c * (ka.z + k4.z),
                                      hb.w + c * (ka.w + k4.w));
            if (LAST) {
                reinterpret_cast<float4*>(out + (size_t)i * HID)[q] = hnew;
            } else {
                reinterpret_cast<float4*>(h + (size_t)i * HID)[q] = hnew;
            }
            acc[4*q+0] = hnew.x; acc[4*q+1] = hnew.y;
            acc[4*q+2] = hnew.z; acc[4*q+3] = hnew.w;
        }
    }
    if (LAST) return;
    // hn = LN(acc; g_ode, b_ode)
    float m = 0.f;
    #pragma unroll
    for (int f = 0; f < HID; ++f) m += acc[f];
    m *= (1.0f / HID);
    float var = 0.f;
    #pragma unroll
    for (int f = 0; f < HID; ++f) { float d = acc[f] - m; var += d * d; }
    var *= (1.0f / HID);
    float rs = rsqrtf(var + 1e-5f);
    float4* hw = reinterpret_cast<float4*>(hn + (size_t)i * HID);
    #pragma unroll
    for (int q = 0; q < HID / 4; ++q)
        hw[q] = make_float4((acc[4*q+0] - m) * rs * sGo[4*q+0] + sBo[4*q+0],
                            (acc[4*q+1] - m) * rs * sGo[4*q+1] + sBo[4*q+1],
                            (acc[4*q+2] - m) * rs * sGo[4*q+2] + sBo[4*q+2],
                            (acc[4*q+3] - m) * rs * sGo[4*q+3] + sBo[4*q+3]);
}

// ---------------------------------------------------------------------------

extern "C" void kernel_launch(void* const* d_in, const int* in_sizes, int n_in,
                              void* d_out, int out_size, void* d_ws, size_t ws_size,
                              hipStream_t stream) {
    const float* x      = (const float*)d_in[0];
    const int*   eip    = (const int*)d_in[1];
    const int*   ein    = (const int*)d_in[2];
    const float* t      = (const float*)d_in[3];
    const float* w_enc  = (const float*)d_in[4];
    const float* b_enc  = (const float*)d_in[5];
    const float* g_feat = (const float*)d_in[6];
    const float* b_feat = (const float*)d_in[7];
    const float* w_pos  = (const float*)d_in[8];
    const float* b_pos  = (const float*)d_in[9];
    const float* w_neg  = (const float*)d_in[10];
    const float* b_neg  = (const float*)d_in[11];
    const float* w_psi  = (const float*)d_in[12];
    const float* g_ode  = (const float*)d_in[13];
    const float* b_ode  = (const float*)d_in[14];

    const int n = in_sizes[0] / NFEAT;      // 100000
    const int E = in_sizes[1] / 2;          // 1600000

    char* p = (char*)d_ws;
    auto carve = [&](size_t bytes) {
        void* r = (void*)p;
        p += (bytes + 255) & ~(size_t)255;
        return r;
    };
    float* h       = (float*)carve((size_t)n * HID * 4);
    float* hn      = (float*)carve((size_t)n * HID * 4);
    float* kacc    = (float*)carve((size_t)n * HID * 4);
    float* aggp    = (float*)carve((size_t)n * HID * 4);
    float* aggn    = (float*)carve((size_t)n * HID * 4);
    float* dinvP   = (float*)carve((size_t)n * 4);
    float* invdegP = (float*)carve((size_t)n * 4);
    float* dinvN   = (float*)carve((size_t)n * 4);
    float* invdegN = (float*)carve((size_t)n * 4);
    int*   cntP    = (int*)carve((size_t)n * 4);
    int*   cntN    = (int*)carve((size_t)n * 4);
    int*   rpP     = (int*)carve((size_t)(n + 1) * 4);
    int*   rpN     = (int*)carve((size_t)(n + 1) * 4);
    int*   curP    = (int*)carve((size_t)n * 4);
    int*   curN    = (int*)carve((size_t)n * 4);
    int*   colP    = (int*)carve((size_t)E * 4);
    int*   colN    = (int*)carve((size_t)E * 4);
    float* cofP    = (float*)carve((size_t)E * 4);
    float* cofN    = (float*)carve((size_t)E * 4);
    (void)ws_size; (void)n_in; (void)out_size;

    const int* srcP = eip;
    const int* dstP = eip + E;
    const int* srcN = ein;
    const int* dstN = ein + E;

    // --- graph preprocessing (amortized over 64 aggregations) ---
    hipMemsetAsync(cntP, 0, (size_t)n * 4, stream);
    hipMemsetAsync(cntN, 0, (size_t)n * 4, stream);
    hist_kernel<<<2048, 256, 0, stream>>>(dstP, dstN, cntP, cntN, E);
    deg_kernel<<<(n + 255) / 256, 256, 0, stream>>>(cntP, cntN, dinvP, invdegP, dinvN, invdegN, n);
    scan_kernel<<<2, 1024, 0, stream>>>(cntP, cntN, rpP, rpN, n);
    hipMemcpyAsync(curP, rpP, (size_t)n * 4, hipMemcpyDeviceToDevice, stream);
    hipMemcpyAsync(curN, rpN, (size_t)n * 4, hipMemcpyDeviceToDevice, stream);
    fill_kernel<<<2048, 256, 0, stream>>>(srcP, dstP, srcN, dstN, dinvP, dinvN,
                                          curP, curN, colP, cofP, colN, cofN, E);

    // --- encoder: h0 and its ode-LN ---
    encoder_kernel<<<(n + 255) / 256, 256, 0, stream>>>(x, w_enc, b_enc, g_feat, b_feat,
                                                        g_ode, b_ode, h, hn, n);

    // --- 8 RK4 steps x 4 stages ---
    const int nbg = (n + 7) / 8;
    const int pg = (n + 255) / 256;
    for (int s = 0; s < 8; ++s) {
        for (int st = 0; st < 4; ++st) {
            spmm_kernel<<<2 * nbg, 256, 0, stream>>>(hn, rpP, colP, cofP, invdegP,
                                                     rpN, colN, cofN, invdegN,
                                                     aggp, aggn, n, nbg);
            bool last = (s == 7 && st == 3);
            if (st == 0)
                post_kernel<0, false><<<pg, 256, 0, stream>>>(aggp, aggn, w_pos, b_pos, w_neg, b_neg,
                    w_psi, g_ode, b_ode, t, h, hn, kacc, (float*)d_out, n);
            else if (st == 1)
                post_kernel<1, false><<<pg, 256, 0, stream>>>(aggp, aggn, w_pos, b_pos, w_neg, b_neg,
                    w_psi, g_ode, b_ode, t, h, hn, kacc, (float*)d_out, n);
            else if (st == 2)
                post_kernel<2, false><<<pg, 256, 0, stream>>>(aggp, aggn, w_pos, b_pos, w_neg, b_neg,
                    w_psi, g_ode, b_ode, t, h, hn, kacc, (float*)d_out, n);
            else if (!last)
                post_kernel<3, false><<<pg, 256, 0, stream>>>(aggp, aggn, w_pos, b_pos, w_neg, b_neg,
                    w_psi, g_ode, b_ode, t, h, hn, kacc, (float*)d_out, n);
            else
                post_kernel<3, true><<<pg, 256, 0, stream>>>(aggp, aggn, w_pos, b_pos, w_neg, b_neg,
                    w_psi, g_ode, b_ode, t, h, hn, kacc, (float*)d_out, n);
        }
    }
}

// Round 3
// 5048.381 us; speedup vs baseline: 9.7021x; 9.7021x over previous
//
#include <hip/hip_runtime.h>

#define HID 32
#define NFEAT 64

// ---------------------------------------------------------------------------
// Graph preprocessing (loop-invariant, rebuilt every launch)
// ---------------------------------------------------------------------------

__global__ void hist_kernel(const int* __restrict__ dstP, const int* __restrict__ dstN,
                            int* __restrict__ cntP, int* __restrict__ cntN, int E) {
    int stride = gridDim.x * blockDim.x;
    for (int idx = blockIdx.x * blockDim.x + threadIdx.x; idx < 2 * E; idx += stride) {
        if (idx < E) atomicAdd(&cntP[dstP[idx]], 1);
        else         atomicAdd(&cntN[dstN[idx - E]], 1);
    }
}

__global__ void deg_kernel(const int* __restrict__ cntP, const int* __restrict__ cntN,
                           float* __restrict__ dinvP, float* __restrict__ invdegP,
                           float* __restrict__ dinvN, float* __restrict__ invdegN, int n) {
    int i = blockIdx.x * blockDim.x + threadIdx.x;
    if (i >= n) return;
    float dp = (float)cntP[i] + 1.0f;
    dinvP[i] = rsqrtf(dp);
    invdegP[i] = 1.0f / dp;
    float dn = (float)cntN[i] + 1.0f;
    dinvN[i] = rsqrtf(dn);
    invdegN[i] = 1.0f / dn;
}

// Exclusive scan of cnt -> row_ptr (one block per graph, sequential chunks).
__global__ void scan_kernel(const int* __restrict__ cntP, const int* __restrict__ cntN,
                            int* __restrict__ rpP, int* __restrict__ rpN, int n) {
    const int* cnt = blockIdx.x ? cntN : cntP;
    int* rp = blockIdx.x ? rpN : rpP;
    __shared__ int buf[1024];
    __shared__ int carry;
    int tid = threadIdx.x;
    if (tid == 0) carry = 0;
    __syncthreads();
    for (int base = 0; base < n; base += 1024) {
        int i = base + tid;
        int v = (i < n) ? cnt[i] : 0;
        buf[tid] = v;
        __syncthreads();
        for (int off = 1; off < 1024; off <<= 1) {
            int t = (tid >= off) ? buf[tid - off] : 0;
            __syncthreads();
            buf[tid] += t;
            __syncthreads();
        }
        int c = carry;
        if (i < n) rp[i] = c + buf[tid] - v;   // exclusive
        __syncthreads();
        if (tid == 1023) carry = c + buf[1023];
        __syncthreads();
    }
    if (tid == 0) rp[n] = carry;
}

__global__ void fill_kernel(const int* __restrict__ srcP, const int* __restrict__ dstP,
                            const int* __restrict__ srcN, const int* __restrict__ dstN,
                            const float* __restrict__ dinvP, const float* __restrict__ dinvN,
                            int* __restrict__ curP, int* __restrict__ curN,
                            int* __restrict__ colP, float* __restrict__ cofP,
                            int* __restrict__ colN, float* __restrict__ cofN, int E) {
    int stride = gridDim.x * blockDim.x;
    for (int idx = blockIdx.x * blockDim.x + threadIdx.x; idx < 2 * E; idx += stride) {
        if (idx < E) {
            int s = srcP[idx], d = dstP[idx];
            int p = atomicAdd(&curP[d], 1);
            colP[p] = s;
            cofP[p] = dinvP[s] * dinvP[d];
        } else {
            int e = idx - E;
            int s = srcN[e], d = dstN[e];
            int p = atomicAdd(&curN[d], 1);
            colN[p] = s;
            cofN[p] = dinvN[s] * dinvN[d];
        }
    }
}

// ---------------------------------------------------------------------------
// Combined weights: Wpp = Wp @ Psi_top, Wnn = Wn @ Psi_bot,
// cbias = bp @ Psi_top + bn @ Psi_bot.   (one 1024-thread block, runs once)
// ---------------------------------------------------------------------------

__global__ void wcomb_kernel(const float* __restrict__ wp, const float* __restrict__ bp,
                             const float* __restrict__ wn, const float* __restrict__ bn,
                             const float* __restrict__ psi,
                             float* __restrict__ wpp, float* __restrict__ wnn,
                             float* __restrict__ cb) {
    int tid = threadIdx.x;
    int j = tid >> 5, f = tid & 31;
    float sp = 0.f, sn = 0.f;
    #pragma unroll
    for (int k = 0; k < HID; ++k) {
        sp += wp[j * HID + k] * psi[k * HID + f];
        sn += wn[j * HID + k] * psi[(HID + k) * HID + f];
    }
    wpp[j * HID + f] = sp;
    wnn[j * HID + f] = sn;
    if (j == 0) {
        float s = 0.f;
        #pragma unroll
        for (int k = 0; k < HID; ++k)
            s += bp[k] * psi[k * HID + f] + bn[k] * psi[(HID + k) * HID + f];
        cb[f] = s;
    }
}

// ---------------------------------------------------------------------------
// Encoder: h0 = LN(x @ w_enc + b_enc; g_feat,b_feat); hn = LN(h0; g_ode,b_ode)
// ---------------------------------------------------------------------------

__global__ __launch_bounds__(256) void encoder_kernel(
        const float* __restrict__ x, const float* __restrict__ w_enc,
        const float* __restrict__ b_enc, const float* __restrict__ g_feat,
        const float* __restrict__ b_feat, const float* __restrict__ g_ode,
        const float* __restrict__ b_ode,
        float* __restrict__ h, float* __restrict__ hn, int n) {
    __shared__ float sW[NFEAT][HID];
    __shared__ float sBe[HID], sGf[HID], sBf[HID], sGo[HID], sBo[HID];
    for (int k = threadIdx.x; k < NFEAT * HID; k += blockDim.x)
        sW[k >> 5][k & 31] = w_enc[k];
    if (threadIdx.x < HID) {
        sBe[threadIdx.x] = b_enc[threadIdx.x];
        sGf[threadIdx.x] = g_feat[threadIdx.x];
        sBf[threadIdx.x] = b_feat[threadIdx.x];
        sGo[threadIdx.x] = g_ode[threadIdx.x];
        sBo[threadIdx.x] = b_ode[threadIdx.x];
    }
    __syncthreads();
    int i = blockIdx.x * blockDim.x + threadIdx.x;
    if (i >= n) return;

    float acc[HID];
    #pragma unroll
    for (int f = 0; f < HID; ++f) acc[f] = sBe[f];
    const float4* xr = reinterpret_cast<const float4*>(x + (size_t)i * NFEAT);
    #pragma unroll 2
    for (int q = 0; q < NFEAT / 4; ++q) {
        float4 a = xr[q];
        #pragma unroll
        for (int r = 0; r < 4; ++r) {
            float av = (r == 0) ? a.x : (r == 1) ? a.y : (r == 2) ? a.z : a.w;
            const float4* wr = reinterpret_cast<const float4*>(sW[4 * q + r]);
            #pragma unroll
            for (int f4 = 0; f4 < HID / 4; ++f4) {
                float4 w = wr[f4];
                acc[4 * f4 + 0] += av * w.x;
                acc[4 * f4 + 1] += av * w.y;
                acc[4 * f4 + 2] += av * w.z;
                acc[4 * f4 + 3] += av * w.w;
            }
        }
    }
    // LN (feat)
    float m = 0.f;
    #pragma unroll
    for (int f = 0; f < HID; ++f) m += acc[f];
    m *= (1.0f / HID);
    float var = 0.f;
    #pragma unroll
    for (int f = 0; f < HID; ++f) { float d = acc[f] - m; var += d * d; }
    var *= (1.0f / HID);
    float rs = rsqrtf(var + 1e-5f);
    #pragma unroll
    for (int f = 0; f < HID; ++f) acc[f] = (acc[f] - m) * rs * sGf[f] + sBf[f];

    float4* hw = reinterpret_cast<float4*>(h + (size_t)i * HID);
    #pragma unroll
    for (int q = 0; q < HID / 4; ++q)
        hw[q] = make_float4(acc[4*q], acc[4*q+1], acc[4*q+2], acc[4*q+3]);

    // LN (ode) -> hn
    m = 0.f;
    #pragma unroll
    for (int f = 0; f < HID; ++f) m += acc[f];
    m *= (1.0f / HID);
    var = 0.f;
    #pragma unroll
    for (int f = 0; f < HID; ++f) { float d = acc[f] - m; var += d * d; }
    var *= (1.0f / HID);
    rs = rsqrtf(var + 1e-5f);
    float4* hnw = reinterpret_cast<float4*>(hn + (size_t)i * HID);
    #pragma unroll
    for (int q = 0; q < HID / 4; ++q)
        hnw[q] = make_float4((acc[4*q+0] - m) * rs * sGo[4*q+0] + sBo[4*q+0],
                             (acc[4*q+1] - m) * rs * sGo[4*q+1] + sBo[4*q+1],
                             (acc[4*q+2] - m) * rs * sGo[4*q+2] + sBo[4*q+2],
                             (acc[4*q+3] - m) * rs * sGo[4*q+3] + sBo[4*q+3]);
}

// ---------------------------------------------------------------------------
// SpMM over hn (both graphs in one grid): agg[i] = invdeg[i]*hn[i] + sum coef*hn[col]
// 32 lanes per node; edge metadata loaded coalesced per 32-edge chunk, then
// broadcast via __shfl within the 32-lane group.
// ---------------------------------------------------------------------------

__global__ __launch_bounds__(256) void spmm_kernel(
        const float* __restrict__ hn,
        const int* __restrict__ rpP, const int* __restrict__ colP,
        const float* __restrict__ cofP, const float* __restrict__ invdegP,
        const int* __restrict__ rpN, const int* __restrict__ colN,
        const float* __restrict__ cofN, const float* __restrict__ invdegN,
        float* __restrict__ aggp, float* __restrict__ aggn, int n, int nbg) {
    int b = blockIdx.x;
    int graph = (b >= nbg);
    if (graph) b -= nbg;
    int i = b * 8 + (threadIdx.x >> 5);
    int f = threadIdx.x & 31;
    if (i >= n) return;
    const int*   rp  = graph ? rpN  : rpP;
    const int*   col = graph ? colN : colP;
    const float* cof = graph ? cofN : cofP;
    const float* ivd = graph ? invdegN : invdegP;
    float*       out = graph ? aggn : aggp;
    int beg = rp[i], end = rp[i + 1];
    float acc = ivd[i] * hn[(size_t)i * HID + f];
    for (int e0 = beg; e0 < end; e0 += 32) {
        int idx = e0 + f;
        int   jj = (idx < end) ? col[idx] : 0;
        float cc = (idx < end) ? cof[idx] : 0.0f;
        int cnt = min(32, end - e0);
        for (int u = 0; u < cnt; ++u) {
            int j   = __shfl(jj, u, 32);
            float c = __shfl(cc, u, 32);
            acc += c * hn[(size_t)j * HID + f];
        }
    }
    out[(size_t)i * HID + f] = acc;
}

// ---------------------------------------------------------------------------
// Fused pointwise kernel: combined matmul + tanh + clip + RK4 stage + LN(next)
// ---------------------------------------------------------------------------

template<int STAGE, bool LAST>
__global__ __launch_bounds__(256) void post_kernel(
        const float* __restrict__ aggp, const float* __restrict__ aggn,
        const float* __restrict__ wpp, const float* __restrict__ wnn,
        const float* __restrict__ cb,
        const float* __restrict__ g_ode, const float* __restrict__ b_ode,
        const float* __restrict__ t,
        float* __restrict__ h, float* __restrict__ hn, float* __restrict__ kacc,
        float* __restrict__ out, int n) {
    __shared__ float sWp[HID][HID];
    __shared__ float sWn[HID][HID];
    __shared__ float sCb[HID], sGo[HID], sBo[HID];
    for (int k = threadIdx.x; k < HID * HID; k += blockDim.x) {
        sWp[k >> 5][k & 31] = wpp[k];
        sWn[k >> 5][k & 31] = wnn[k];
    }
    if (threadIdx.x < HID) {
        sCb[threadIdx.x] = cb[threadIdx.x];
        sGo[threadIdx.x] = g_ode[threadIdx.x];
        sBo[threadIdx.x] = b_ode[threadIdx.x];
    }
    __syncthreads();
    int i = blockIdx.x * blockDim.x + threadIdx.x;
    if (i >= n) return;
    const float dt = (t[1] - t[0]) * 0.125f;

    float acc[HID];
    #pragma unroll
    for (int f = 0; f < HID; ++f) acc[f] = sCb[f];

    const float4* ap = reinterpret_cast<const float4*>(aggp + (size_t)i * HID);
    #pragma unroll 2
    for (int q = 0; q < HID / 4; ++q) {
        float4 a = ap[q];
        #pragma unroll
        for (int r = 0; r < 4; ++r) {
            float av = (r == 0) ? a.x : (r == 1) ? a.y : (r == 2) ? a.z : a.w;
            const float4* wr = reinterpret_cast<const float4*>(sWp[4 * q + r]);
            #pragma unroll
            for (int f4 = 0; f4 < HID / 4; ++f4) {
                float4 w = wr[f4];
                acc[4 * f4 + 0] += av * w.x;
                acc[4 * f4 + 1] += av * w.y;
                acc[4 * f4 + 2] += av * w.z;
                acc[4 * f4 + 3] += av * w.w;
            }
        }
    }
    const float4* an = reinterpret_cast<const float4*>(aggn + (size_t)i * HID);
    #pragma unroll 2
    for (int q = 0; q < HID / 4; ++q) {
        float4 a = an[q];
        #pragma unroll
        for (int r = 0; r < 4; ++r) {
            float av = (r == 0) ? a.x : (r == 1) ? a.y : (r == 2) ? a.z : a.w;
            const float4* wr = reinterpret_cast<const float4*>(sWn[4 * q + r]);
            #pragma unroll
            for (int f4 = 0; f4 < HID / 4; ++f4) {
                float4 w = wr[f4];
                acc[4 * f4 + 0] += av * w.x;
                acc[4 * f4 + 1] += av * w.y;
                acc[4 * f4 + 2] += av * w.z;
                acc[4 * f4 + 3] += av * w.w;
            }
        }
    }

    // k = clip(tanh(acc) - 0.1*hn, -50, 50)
    {
        const float4* hr = reinterpret_cast<const float4*>(hn + (size_t)i * HID);
        #pragma unroll
        for (int q = 0; q < HID / 4; ++q) {
            float4 hv = hr[q];
            float d0 = tanhf(acc[4*q+0]) - 0.1f * hv.x;
            float d1 = tanhf(acc[4*q+1]) - 0.1f * hv.y;
            float d2 = tanhf(acc[4*q+2]) - 0.1f * hv.z;
            float d3 = tanhf(acc[4*q+3]) - 0.1f * hv.w;
            acc[4*q+0] = fminf(fmaxf(d0, -50.0f), 50.0f);
            acc[4*q+1] = fminf(fmaxf(d1, -50.0f), 50.0f);
            acc[4*q+2] = fminf(fmaxf(d2, -50.0f), 50.0f);
            acc[4*q+3] = fminf(fmaxf(d3, -50.0f), 50.0f);
        }
    }
    // RK4 stage; acc := h_next (input to next ode eval)
    float4* kar = reinterpret_cast<float4*>(kacc + (size_t)i * HID);
    const float4* hbr = reinterpret_cast<const float4*>(h + (size_t)i * HID);
    #pragma unroll
    for (int q = 0; q < HID / 4; ++q) {
        float4 hb = hbr[q];
        float4 k4 = make_float4(acc[4*q], acc[4*q+1], acc[4*q+2], acc[4*q+3]);
        if (STAGE == 0) {
            kar[q] = k4;
            acc[4*q+0] = hb.x + 0.5f * dt * k4.x;
            acc[4*q+1] = hb.y + 0.5f * dt * k4.y;
            acc[4*q+2] = hb.z + 0.5f * dt * k4.z;
            acc[4*q+3] = hb.w + 0.5f * dt * k4.w;
        } else if (STAGE == 1 || STAGE == 2) {
            float4 ka = kar[q];
            ka.x += 2.0f * k4.x; ka.y += 2.0f * k4.y;
            ka.z += 2.0f * k4.z; ka.w += 2.0f * k4.w;
            kar[q] = ka;
            const float a = (STAGE == 1) ? 0.5f * dt : dt;
            acc[4*q+0] = hb.x + a * k4.x;
            acc[4*q+1] = hb.y + a * k4.y;
            acc[4*q+2] = hb.z + a * k4.z;
            acc[4*q+3] = hb.w + a * k4.w;
        } else {
            float4 ka = kar[q];
            const float c = dt * (1.0f / 6.0f);
            float4 hnew = make_float4(hb.x + c * (ka.x + k4.x),
                                      hb.y + c * (ka.y + k4.y),
                                      hb.z + c * (ka.z + k4.z),
                                      hb.w + c * (ka.w + k4.w));
            if (LAST) {
                reinterpret_cast<float4*>(out + (size_t)i * HID)[q] = hnew;
            } else {
                reinterpret_cast<float4*>(h + (size_t)i * HID)[q] = hnew;
            }
            acc[4*q+0] = hnew.x; acc[4*q+1] = hnew.y;
            acc[4*q+2] = hnew.z; acc[4*q+3] = hnew.w;
        }
    }
    if (LAST) return;
    // hn = LN(acc; g_ode, b_ode)
    float m = 0.f;
    #pragma unroll
    for (int f = 0; f < HID; ++f) m += acc[f];
    m *= (1.0f / HID);
    float var = 0.f;
    #pragma unroll
    for (int f = 0; f < HID; ++f) { float d = acc[f] - m; var += d * d; }
    var *= (1.0f / HID);
    float rs = rsqrtf(var + 1e-5f);
    float4* hw = reinterpret_cast<float4*>(hn + (size_t)i * HID);
    #pragma unroll
    for (int q = 0; q < HID / 4; ++q)
        hw[q] = make_float4((acc[4*q+0] - m) * rs * sGo[4*q+0] + sBo[4*q+0],
                            (acc[4*q+1] - m) * rs * sGo[4*q+1] + sBo[4*q+1],
                            (acc[4*q+2] - m) * rs * sGo[4*q+2] + sBo[4*q+2],
                            (acc[4*q+3] - m) * rs * sGo[4*q+3] + sBo[4*q+3]);
}

// ---------------------------------------------------------------------------

extern "C" void kernel_launch(void* const* d_in, const int* in_sizes, int n_in,
                              void* d_out, int out_size, void* d_ws, size_t ws_size,
                              hipStream_t stream) {
    const float* x      = (const float*)d_in[0];
    const int*   eip    = (const int*)d_in[1];
    const int*   ein    = (const int*)d_in[2];
    const float* t      = (const float*)d_in[3];
    const float* w_enc  = (const float*)d_in[4];
    const float* b_enc  = (const float*)d_in[5];
    const float* g_feat = (const float*)d_in[6];
    const float* b_feat = (const float*)d_in[7];
    const float* w_pos  = (const float*)d_in[8];
    const float* b_pos  = (const float*)d_in[9];
    const float* w_neg  = (const float*)d_in[10];
    const float* b_neg  = (const float*)d_in[11];
    const float* w_psi  = (const float*)d_in[12];
    const float* g_ode  = (const float*)d_in[13];
    const float* b_ode  = (const float*)d_in[14];

    const int n = in_sizes[0] / NFEAT;      // 100000
    const int E = in_sizes[1] / 2;          // 1600000

    char* p = (char*)d_ws;
    auto carve = [&](size_t bytes) {
        void* r = (void*)p;
        p += (bytes + 255) & ~(size_t)255;
        return r;
    };
    float* h       = (float*)carve((size_t)n * HID * 4);
    float* hn      = (float*)carve((size_t)n * HID * 4);
    float* kacc    = (float*)carve((size_t)n * HID * 4);
    float* aggp    = (float*)carve((size_t)n * HID * 4);
    float* aggn    = (float*)carve((size_t)n * HID * 4);
    float* dinvP   = (float*)carve((size_t)n * 4);
    float* invdegP = (float*)carve((size_t)n * 4);
    float* dinvN   = (float*)carve((size_t)n * 4);
    float* invdegN = (float*)carve((size_t)n * 4);
    int*   cntP    = (int*)carve((size_t)n * 4);
    int*   cntN    = (int*)carve((size_t)n * 4);
    int*   rpP     = (int*)carve((size_t)(n + 1) * 4);
    int*   rpN     = (int*)carve((size_t)(n + 1) * 4);
    int*   curP    = (int*)carve((size_t)n * 4);
    int*   curN    = (int*)carve((size_t)n * 4);
    int*   colP    = (int*)carve((size_t)E * 4);
    int*   colN    = (int*)carve((size_t)E * 4);
    float* cofP    = (float*)carve((size_t)E * 4);
    float* cofN    = (float*)carve((size_t)E * 4);
    float* wpp     = (float*)carve((size_t)HID * HID * 4);
    float* wnn     = (float*)carve((size_t)HID * HID * 4);
    float* cbias   = (float*)carve((size_t)HID * 4);
    (void)ws_size; (void)n_in; (void)out_size;

    const int* srcP = eip;
    const int* dstP = eip + E;
    const int* srcN = ein;
    const int* dstN = ein + E;

    // --- graph preprocessing (amortized over 64 aggregations) ---
    hipMemsetAsync(cntP, 0, (size_t)n * 4, stream);
    hipMemsetAsync(cntN, 0, (size_t)n * 4, stream);
    hist_kernel<<<2048, 256, 0, stream>>>(dstP, dstN, cntP, cntN, E);
    deg_kernel<<<(n + 255) / 256, 256, 0, stream>>>(cntP, cntN, dinvP, invdegP, dinvN, invdegN, n);
    scan_kernel<<<2, 1024, 0, stream>>>(cntP, cntN, rpP, rpN, n);
    hipMemcpyAsync(curP, rpP, (size_t)n * 4, hipMemcpyDeviceToDevice, stream);
    hipMemcpyAsync(curN, rpN, (size_t)n * 4, hipMemcpyDeviceToDevice, stream);
    fill_kernel<<<2048, 256, 0, stream>>>(srcP, dstP, srcN, dstN, dinvP, dinvN,
                                          curP, curN, colP, cofP, colN, cofN, E);
    wcomb_kernel<<<1, 1024, 0, stream>>>(w_pos, b_pos, w_neg, b_neg, w_psi, wpp, wnn, cbias);

    // --- encoder: h0 and its ode-LN ---
    encoder_kernel<<<(n + 255) / 256, 256, 0, stream>>>(x, w_enc, b_enc, g_feat, b_feat,
                                                        g_ode, b_ode, h, hn, n);

    // --- 8 RK4 steps x 4 stages ---
    const int nbg = (n + 7) / 8;
    const int pg = (n + 255) / 256;
    for (int s = 0; s < 8; ++s) {
        for (int st = 0; st < 4; ++st) {
            spmm_kernel<<<2 * nbg, 256, 0, stream>>>(hn, rpP, colP, cofP, invdegP,
                                                     rpN, colN, cofN, invdegN,
                                                     aggp, aggn, n, nbg);
            bool last = (s == 7 && st == 3);
            if (st == 0)
                post_kernel<0, false><<<pg, 256, 0, stream>>>(aggp, aggn, wpp, wnn, cbias,
                    g_ode, b_ode, t, h, hn, kacc, (float*)d_out, n);
            else if (st == 1)
                post_kernel<1, false><<<pg, 256, 0, stream>>>(aggp, aggn, wpp, wnn, cbias,
                    g_ode, b_ode, t, h, hn, kacc, (float*)d_out, n);
            else if (st == 2)
                post_kernel<2, false><<<pg, 256, 0, stream>>>(aggp, aggn, wpp, wnn, cbias,
                    g_ode, b_ode, t, h, hn, kacc, (float*)d_out, n);
            else if (!last)
                post_kernel<3, false><<<pg, 256, 0, stream>>>(aggp, aggn, wpp, wnn, cbias,
                    g_ode, b_ode, t, h, hn, kacc, (float*)d_out, n);
            else
                post_kernel<3, true><<<pg, 256, 0, stream>>>(aggp, aggn, wpp, wnn, cbias,
                    g_ode, b_ode, t, h, hn, kacc, (float*)d_out, n);
        }
    }
}